// Round 1
// baseline (300.719 us; speedup 1.0000x reference)
//
#include <hip/hip_runtime.h>
#include <math.h>

#define NB 16
#define NC 8
#define HH 512
#define WW 512
#define HW (HH * WW)
#define CHW (NC * HW)

#define LOG2E 1.44269504088896f
#define LN2   0.693147180559945f
#define CLMP  144.269504088896f   /* 100 * log2(e): clamp in log2 units */

typedef const __attribute__((address_space(1))) void* gvp;
typedef __attribute__((address_space(3))) void*       lvp;

__device__ __forceinline__ float sigf(float x) {
    return __fdividef(1.0f, 1.0f + __expf(-x));
}

// -max(log(q), -100) in log2 units == min(-log2(q), 144.2695)
__device__ __forceinline__ float bce2(float t, float v) {
    float q = (t > 0.5f) ? v : (1.0f - v);
    return fminf(-__builtin_amdgcn_logf(q), CLMP);
}

__device__ __forceinline__ void ld4(const float* p, float* o) {
    float4 v = *(const float4*)p;
    o[0] = v.x; o[1] = v.y; o[2] = v.z; o[3] = v.w;
}

// Block = 256 threads, 2 rows x 512 px per block.
// LDS now holds SIGMOID values (p), 16 planes x 512 = 32 KB (was 22 raw planes,
// 44 KB) -> 4 blocks/CU instead of 3. Each c_map element is sigmoided exactly
// once; the conmap BCE is folded into the sigmoid pass via
//   -log p = log(1+e),  -log(1-p) = c + log(1+e),  e = exp(-c).
// Plane map:
//   0,1,2  : row h0-1, ch 5,6,7   (DMA raw -> sigmoided in place)
//   3,4,5  : row h0+2, ch 0,1,2   (DMA raw -> sigmoided in place)
//   6..10  : row h0  , ch 3..7    (p written from r=0 threads' registers)
//   11..15 : row h0+1, ch 0..4    (p written from r=1 threads' registers)
__global__ __launch_bounds__(256, 4) void bicon_loss_kernel(
    const float* __restrict__ c_map,
    const float* __restrict__ target,
    const float* __restrict__ con_target,
    float* __restrict__ out)
{
    __shared__ float lds[16][WW];

    const int b    = blockIdx.x >> 8;
    const int h0   = (blockIdx.x & 255) << 1;
    const int tid  = threadIdx.x;
    const int wave = tid >> 6;
    const int lane = tid & 63;

    // ---- async DMA: 6 halo planes = 12 segments of 1 KB, 3 per wave ----
    for (int s = wave; s < 12; s += 4) {
        const int plane = s >> 1, half = s & 1;
        int ch, rr;
        if (plane < 3) { ch = 5 + plane; rr = h0 - 1; }
        else           { ch = plane - 3; rr = h0 + 2; }
        rr = rr < 0 ? 0 : (rr > HH - 1 ? HH - 1 : rr);  // clamp; gated off on use
        const float* gp = c_map + b * CHW + ch * HW + rr * WW + half * 256 + lane * 4;
        __builtin_amdgcn_global_load_lds((gvp)gp, (lvp)&lds[plane][half * 256], 16, 0, 0);
    }

    const int r   = tid >> 7;            // wave-uniform tile row 0/1
    const int px0 = (tid & 127) << 2;
    const int gr  = h0 + r;

    // ---- direct VGPR loads: center c_map 8x16B, con_target 8x16B, target ----
    const float* cm = c_map + b * CHW + gr * WW + px0;
    float cv[8][4];
    #pragma unroll
    for (int c = 0; c < 8; ++c) ld4(cm + c * HW, cv[c]);

    const float* ct = con_target + b * CHW + gr * WW + px0;
    float tv[8][4];
    #pragma unroll
    for (int c = 0; c < 8; ++c) ld4(ct + c * HW, tv[c]);
    float tg[4];
    ld4(target + b * HW + gr * WW + px0, tg);

    __syncthreads();   // drain DMA

    // ---- sigmoid halo planes in place: 768 float4 / 256 threads = 3 each ----
    #pragma unroll
    for (int k = 0; k < 3; ++k) {
        float4* lp = reinterpret_cast<float4*>(&lds[0][0]) + (k * 256 + tid);
        float4 v = *lp;
        v.x = sigf(v.x); v.y = sigf(v.y); v.z = sigf(v.z); v.w = sigf(v.w);
        *lp = v;
    }

    // ---- center pass: p + conmap-BCE fused, one exp + one log per element ----
    float sp[8][4];
    float acc_con = 0.0f;                       // log2 units
    #pragma unroll
    for (int c = 0; c < 8; ++c) {
        #pragma unroll
        for (int j = 0; j < 4; ++j) {
            const float cl2 = cv[c][j] * LOG2E;
            const float e   = __builtin_amdgcn_exp2f(-cl2);
            const float s   = 1.0f + e;
            const float Lg  = __builtin_amdgcn_logf(s);   // log2(1+e) = -log2(p)
            sp[c][j] = __builtin_amdgcn_rcpf(s);          // p
            const float extra = (tv[c][j] > 0.5f) ? 0.0f : cl2;
            acc_con += fminf(Lg + extra, CLMP);
        }
    }

    // publish the p-planes neighbors need (branch is wave-uniform)
    if (r == 0) {
        #pragma unroll
        for (int c = 3; c < 8; ++c)
            *(float4*)&lds[3 + c][px0] =
                make_float4(sp[c][0], sp[c][1], sp[c][2], sp[c][3]);
    } else {
        #pragma unroll
        for (int c = 0; c < 5; ++c)
            *(float4*)&lds[11 + c][px0] =
                make_float4(sp[c][0], sp[c][1], sp[c][2], sp[c][3]);
    }

    __syncthreads();

    const bool hu = gr > 0, hd = gr < HH - 1;
    const bool wl = px0 > 0, wr = px0 < WW - 4;

    const int pu5 = r ? 8 : 0,  pu6 = r ? 9 : 1,  pu7 = r ? 10 : 2;
    const int pd0 = r ? 3 : 11, pd1 = r ? 4 : 12, pd2 = r ? 5 : 13;
    const int pe3 = r ? 14 : 6, pe4 = r ? 15 : 7;

    float u5[4], u6[4], u7[4], dd0[4], dd1[4], dd2[4];
    ld4(&lds[pu5][px0], u5);
    ld4(&lds[pu6][px0], u6);
    ld4(&lds[pu7][px0], u7);
    ld4(&lds[pd0][px0], dd0);
    ld4(&lds[pd1][px0], dd1);
    ld4(&lds[pd2][px0], dd2);
    const float e5  = lds[pu5][wr ? px0 + 4 : px0];
    const float e7  = lds[pu7][wl ? px0 - 1 : px0];
    const float e2  = lds[pd2][wr ? px0 + 4 : px0];
    const float e0  = lds[pd0][wl ? px0 - 1 : px0];
    const float m4e = lds[pe4][wl ? px0 - 1 : px0];
    const float m3e = lds[pe3][wr ? px0 + 4 : px0];

    float acc_bi = 0.0f, acc_de = 0.0f;         // log2 units
    #pragma unroll
    for (int j = 0; j < 4; ++j) {
        const float n6  = hu ? u6[j] : 0.0f;
        const float n5  = (j < 3) ? (hu ? u5[j + 1] : 0.0f)
                                  : ((hu && wr) ? e5 : 0.0f);
        const float n7  = (j > 0) ? (hu ? u7[j - 1] : 0.0f)
                                  : ((hu && wl) ? e7 : 0.0f);
        const float dn1 = hd ? dd1[j] : 0.0f;
        const float dn2 = (j < 3) ? (hd ? dd2[j + 1] : 0.0f)
                                  : ((hd && wr) ? e2 : 0.0f);
        const float dn0 = (j > 0) ? (hd ? dd0[j - 1] : 0.0f)
                                  : ((hd && wl) ? e0 : 0.0f);
        const float m4  = (j > 0) ? sp[4][j - 1] : (wl ? m4e : 0.0f);
        const float m3  = (j < 3) ? sp[3][j + 1] : (wr ? m3e : 0.0f);

        const float a1 = sp[3][j] * m4;
        const float a2 = sp[4][j] * m3;
        const float a3 = sp[1][j] * n6;
        const float a4 = sp[6][j] * dn1;
        const float a5 = sp[2][j] * n5;
        const float a6 = sp[5][j] * dn2;
        const float a7 = sp[0][j] * n7;
        const float a8 = sp[7][j] * dn0;

        const float vote[8] = { a7, a3, a5, a1, a2, a6, a4, a8 };

        float sum_conn = 0.0f;
        #pragma unroll
        for (int c = 0; c < 8; ++c) sum_conn += tv[c][j];

        #pragma unroll
        for (int c = 0; c < 8; ++c) acc_bi += bce2(tv[c][j], vote[c]);

        const float glo = (a1 + a2 + a3 + a4 + a5 + a6 + a7 + a8) * 0.125f;
        float mn = vote[0];
        #pragma unroll
        for (int c = 1; c < 8; ++c) mn = fminf(mn, vote[c]);

        const bool edge = (sum_conn < 8.0f) && (sum_conn > 0.0f);
        const float dec = edge ? (1.0f - mn) : glo;
        acc_de += bce2(tg[j], dec);
    }

    float local = fmaf(0.8f, acc_con, fmaf(0.2f, acc_bi, acc_de)) * LN2;

    // ---- reduction: wave64 shuffle -> LDS (reuse plane 0) -> one atomic ----
    #pragma unroll
    for (int off = 32; off > 0; off >>= 1)
        local += __shfl_down(local, off, 64);

    __syncthreads();                 // all LDS reads done before reuse
    if (lane == 0) lds[0][wave] = local;
    __syncthreads();
    if (tid == 0)
        atomicAdd(out, (lds[0][0] + lds[0][1]) + (lds[0][2] + lds[0][3]));
}

extern "C" void kernel_launch(void* const* d_in, const int* in_sizes, int n_in,
                              void* d_out, int out_size, void* d_ws, size_t ws_size,
                              hipStream_t stream) {
    const float* c_map      = (const float*)d_in[0];
    const float* target     = (const float*)d_in[1];
    const float* con_target = (const float*)d_in[2];
    float* out = (float*)d_out;

    hipMemsetAsync(out, 0, sizeof(float), stream);

    const int blocks = NB * (HH / 2);   // 4096
    bicon_loss_kernel<<<blocks, 256, 0, stream>>>(c_map, target, con_target, out);
}

// Round 2
// 288.415 us; speedup vs baseline: 1.0427x; 1.0427x over previous
//
#include <hip/hip_runtime.h>
#include <math.h>

#define NB 16
#define NC 8
#define HH 512
#define WW 512
#define HW (HH * WW)
#define CHW (NC * HW)

#define LOG2E 1.44269504088896f
#define LN2   0.693147180559945f
#define CLMP  144.269504088896f   /* 100 * log2(e): clamp in log2 units */

__device__ __forceinline__ float sigf(float x) {
    return __builtin_amdgcn_rcpf(1.0f + __builtin_amdgcn_exp2f(-x * LOG2E));
}

__device__ __forceinline__ void ld4(const float* p, float* o) {
    float4 v = *(const float4*)p;
    o[0] = v.x; o[1] = v.y; o[2] = v.z; o[3] = v.w;
}

// Barrier-free version. R1 evidence: warm-cache dispatches ran at the same
// ~116 us with ~zero HBM traffic and VALUBusy only 27% -> the kernel was
// latency/structure-bound on the two load/compute lockstep barriers, not on
// HBM or VALU. So: no LDS staging at all. Each thread owns 4 px of one row,
// loads its 6 halo rows directly to VGPRs and recomputes halo sigmoids
// (VALU has 73% headroom). In-row x-shift edges come from lane shuffles;
// the 2 wave-boundary lanes fix up with predicated scalar loads.
// con_target is collapsed to a per-j 8-bit mask (values are exactly 0/1):
// sum_conn == popcount, edge <=> mask not in {0,255}. Saves 32 VGPRs.
__global__ __launch_bounds__(256, 4) void bicon_loss_kernel(
    const float* __restrict__ c_map,
    const float* __restrict__ target,
    const float* __restrict__ con_target,
    float* __restrict__ out)
{
    const int tid  = threadIdx.x;
    const int lane = tid & 63;
    const int wave = tid >> 6;
    const int t    = blockIdx.x * 256 + tid;
    const int g    = t >> 7;          // global row id: 0 .. 16*512-1
    const int b    = g >> 9;
    const int row  = g & 511;
    const int px0  = (t & 127) << 2;  // 0..508, contiguous within a wave

    const bool hu = row > 0, hd = row < HH - 1;
    const bool wl = px0 > 0, wr = px0 < WW - 4;
    const int rU = hu ? row - 1 : 0;      // clamped; values gated at use
    const int rD = hd ? row + 1 : HH - 1;

    const float* base = c_map + b * CHW;
    const int ro = row * WW + px0;

    // ---- halo rows, raw logits -> VGPR (6 x float4) ----
    float u5r[4], u6r[4], u7r[4], d0r[4], d1r[4], d2r[4];
    ld4(base + 5 * HW + rU * WW + px0, u5r);
    ld4(base + 6 * HW + rU * WW + px0, u6r);
    ld4(base + 7 * HW + rU * WW + px0, u7r);
    ld4(base + 0 * HW + rD * WW + px0, d0r);
    ld4(base + 1 * HW + rD * WW + px0, d1r);
    ld4(base + 2 * HW + rD * WW + px0, d2r);

    float tg[4];
    ld4(target + b * HW + ro, tg);

    // ---- wave-boundary edge scalars (2 lanes per wave) ----
    const bool atL = (lane == 0)  && wl;
    const bool atR = (lane == 63) && wr;
    float eL7 = 0.f, eL0 = 0.f, eL4 = 0.f, eR5 = 0.f, eR2 = 0.f, eR3 = 0.f;
    if (atL) {
        eL7 = base[7 * HW + rU  * WW + px0 - 1];
        eL0 = base[0 * HW + rD  * WW + px0 - 1];
        eL4 = base[4 * HW + row * WW + px0 - 1];
    }
    if (atR) {
        eR5 = base[5 * HW + rU  * WW + px0 + 4];
        eR2 = base[2 * HW + rD  * WW + px0 + 4];
        eR3 = base[3 * HW + row * WW + px0 + 4];
    }

    // ---- center pass: sigmoid + fused conmap BCE, one exp+log per elem ----
    //   -log2 p = log2(1+e), -log2(1-p) = c*log2e + log2(1+e), e = 2^(-c*log2e)
    const float* cm = base + ro;
    const float* ct = con_target + b * CHW + ro;
    float sp[8][4];
    int msk[4] = {0, 0, 0, 0};
    float acc_con = 0.0f;                       // log2 units
    #pragma unroll
    for (int c = 0; c < 8; ++c) {
        float cv4[4], tvc[4];
        ld4(cm + c * HW, cv4);
        ld4(ct + c * HW, tvc);
        #pragma unroll
        for (int j = 0; j < 4; ++j) {
            const float cl2 = cv4[j] * LOG2E;
            const float e   = __builtin_amdgcn_exp2f(-cl2);
            const float s   = 1.0f + e;
            const float Lg  = __builtin_amdgcn_logf(s);   // -log2(p)
            sp[c][j] = __builtin_amdgcn_rcpf(s);          // p
            const bool one = tvc[j] > 0.5f;
            msk[j] |= (int)one << c;
            acc_con += fminf(Lg + (one ? 0.0f : cl2), CLMP);
        }
    }

    // ---- in-wave x-shift edges via lane shuffles (uniform control flow) ----
    float u5n = __shfl_down(u5r[0], 1, 64); if (lane == 63) u5n = eR5;
    float u7p = __shfl_up (u7r[3], 1, 64); if (lane == 0)  u7p = eL7;
    float d2n = __shfl_down(d2r[0], 1, 64); if (lane == 63) d2n = eR2;
    float d0p = __shfl_up (d0r[3], 1, 64); if (lane == 0)  d0p = eL0;
    float sp4p = __shfl_up (sp[4][3], 1, 64); if (lane == 0)  sp4p = sigf(eL4);
    float sp3n = __shfl_down(sp[3][0], 1, 64); if (lane == 63) sp3n = sigf(eR3);

    float acc_bi = 0.0f, acc_de = 0.0f;         // log2 units
    #pragma unroll
    for (int j = 0; j < 4; ++j) {
        const float n6  = hu ? sigf(u6r[j]) : 0.0f;
        const float n5  = (((j < 3) ? hu : (hu && wr)))
                          ? sigf((j < 3) ? u5r[j + 1] : u5n) : 0.0f;
        const float n7  = (((j > 0) ? hu : (hu && wl)))
                          ? sigf((j > 0) ? u7r[j - 1] : u7p) : 0.0f;
        const float dn1 = hd ? sigf(d1r[j]) : 0.0f;
        const float dn2 = (((j < 3) ? hd : (hd && wr)))
                          ? sigf((j < 3) ? d2r[j + 1] : d2n) : 0.0f;
        const float dn0 = (((j > 0) ? hd : (hd && wl)))
                          ? sigf((j > 0) ? d0r[j - 1] : d0p) : 0.0f;
        const float m4  = (j > 0) ? sp[4][j - 1] : (wl ? sp4p : 0.0f);
        const float m3  = (j < 3) ? sp[3][j + 1] : (wr ? sp3n : 0.0f);

        const float a1 = sp[3][j] * m4;    // c3 * shift_right(c4)
        const float a2 = sp[4][j] * m3;    // c4 * shift_left(c3)
        const float a3 = sp[1][j] * n6;    // c1 * shift_down(c6)
        const float a4 = sp[6][j] * dn1;   // c6 * shift_up(c1)
        const float a5 = sp[2][j] * n5;    // c2 * left-bottom(c5)
        const float a6 = sp[5][j] * dn2;   // c5 * right-above(c2)
        const float a7 = sp[0][j] * n7;    // c0 * right-bottom(c7)
        const float a8 = sp[7][j] * dn0;   // c7 * left-above(c0)

        const float vote[8] = { a7, a3, a5, a1, a2, a6, a4, a8 };
        const int m = msk[j];

        #pragma unroll
        for (int c = 0; c < 8; ++c) {
            const bool one = (m >> c) & 1;
            const float q = one ? vote[c] : (1.0f - vote[c]);
            acc_bi += fminf(-__builtin_amdgcn_logf(q), CLMP);
        }

        const float glo = (a1 + a2 + a3 + a4 + a5 + a6 + a7 + a8) * 0.125f;
        float mn = vote[0];
        #pragma unroll
        for (int c = 1; c < 8; ++c) mn = fminf(mn, vote[c]);

        const bool edge = (m != 0) && (m != 255);
        const float dec = edge ? (1.0f - mn) : glo;
        const float qd  = (tg[j] > 0.5f) ? dec : (1.0f - dec);
        acc_de += fminf(-__builtin_amdgcn_logf(qd), CLMP);
    }

    float local = fmaf(0.8f, acc_con, fmaf(0.2f, acc_bi, acc_de)) * LN2;

    // ---- reduction: wave64 shuffle -> 4-float LDS -> one atomic ----
    #pragma unroll
    for (int off = 32; off > 0; off >>= 1)
        local += __shfl_down(local, off, 64);

    __shared__ float wsum[4];
    if (lane == 0) wsum[wave] = local;
    __syncthreads();
    if (tid == 0)
        atomicAdd(out, (wsum[0] + wsum[1]) + (wsum[2] + wsum[3]));
}

extern "C" void kernel_launch(void* const* d_in, const int* in_sizes, int n_in,
                              void* d_out, int out_size, void* d_ws, size_t ws_size,
                              hipStream_t stream) {
    const float* c_map      = (const float*)d_in[0];
    const float* target     = (const float*)d_in[1];
    const float* con_target = (const float*)d_in[2];
    float* out = (float*)d_out;

    hipMemsetAsync(out, 0, sizeof(float), stream);

    const int blocks = NB * (HH / 2);   // 4096 blocks x 256 thr, 4 px/thread
    bicon_loss_kernel<<<blocks, 256, 0, stream>>>(c_map, target, con_target, out);
}